// Round 4
// baseline (246.822 us; speedup 1.0000x reference)
//
#include <hip/hip_runtime.h>

// RoIAlign: features (2,256,200,304) fp32 NCHW, rois (512,5) fp32,
// out (512,256,7,7) fp32. OUT=7x7, sampling ratio G=2, scale 0.25.
//
// Round 4: gather restructured to one block per ROI (all 49 bins).
// Round-1 counters showed WRITE_SIZE 75 MB vs 25.7 MB ideal (3x): the 7
// ph-blocks of a roi wrote interleaved 28B runs from different XCDs ->
// partial-line writebacks. One block per roi makes the 50 KB output region
// single-XCD; L2 merges the per-ph partial stores into dense lines.

#define OUT_H 7
#define OUT_W 7
constexpr float SPATIAL_SCALE = 0.25f;
constexpr int CN = 256;   // channels
constexpr int FH = 200;
constexpr int FW = 304;
constexpr int N_IMG = 2;
constexpr int N_ROIS = 512;
constexpr size_t PLANE = (size_t)FH * FW;
constexpr size_t NHWC_ELEMS = (size_t)N_IMG * PLANE * CN;
constexpr size_t NHWC_BF16_BYTES = NHWC_ELEMS * sizeof(unsigned short);

__device__ __forceinline__ unsigned short f2bf_rne(float f) {
    unsigned int u = __float_as_uint(f);
    unsigned int r = (u + 0x7FFFu + ((u >> 16) & 1u)) >> 16;  // RNE
    return (unsigned short)r;
}

// ---------------- transpose NCHW fp32 -> NHWC bf16 ----------------
// grid (N_IMG*FH, FW/16); 256 threads = channels. Each lane reads one
// aligned 64B line of its channel row (pitch 1216 B = 19*64). Wave stores
// 64 consecutive channels of one pixel = 128 B contiguous per instruction.
__global__ __launch_bounds__(256) void nchw_to_nhwc_bf16(
    const float* __restrict__ in, unsigned short* __restrict__ ws)
{
    const int nh = blockIdx.x;            // n*FH + h
    const int n = nh / FH;
    const int h = nh % FH;
    const int c = threadIdx.x;
    const int w0 = blockIdx.y * 16;

    const float* src = in + (((size_t)n * CN + c) * FH + h) * FW + w0;
    unsigned short* dst = ws + (((size_t)n * FH + h) * FW + w0) * CN + c;

    float4 v0 = *(const float4*)(src + 0);
    float4 v1 = *(const float4*)(src + 4);
    float4 v2 = *(const float4*)(src + 8);
    float4 v3 = *(const float4*)(src + 12);

    const float vals[16] = {v0.x, v0.y, v0.z, v0.w, v1.x, v1.y, v1.z, v1.w,
                            v2.x, v2.y, v2.z, v2.w, v3.x, v3.y, v3.z, v3.w};
#pragma unroll
    for (int i = 0; i < 16; ++i) {
        dst[(size_t)i * CN] = f2bf_rne(vals[i]);
    }
}

// ---------------- gather: one block per ROI, all 196 samples ----------------
// 128 threads = 128 channel-pairs (bf16x2 packed loads). Per ph row:
// 112 fully-unrolled uint loads -> deep MLP against L3 latency.
__global__ __launch_bounds__(128) void roi_align_roi_block(
    const unsigned short* __restrict__ ws,
    const float* __restrict__ rois,
    float* __restrict__ out)
{
    const int r = blockIdx.x;
    const int t = threadIdx.x;           // channel pair: channels 2t, 2t+1

    __shared__ float s_roi[5];
    __shared__ int   s_off[196][4];      // 14x14 sample points, 4 corners
    __shared__ float s_w[196][4];
    __shared__ int   s_b;

    if (t < 5) s_roi[t] = rois[r * 5 + t];
    __syncthreads();

    const float x1 = s_roi[1] * SPATIAL_SCALE - 0.5f;
    const float y1 = s_roi[2] * SPATIAL_SCALE - 0.5f;
    const float x2 = s_roi[3] * SPATIAL_SCALE - 0.5f;
    const float y2 = s_roi[4] * SPATIAL_SCALE - 0.5f;
    const float bin_w = (x2 - x1) / OUT_W;
    const float bin_h = (y2 - y1) / OUT_H;

    for (int s = t; s < 196; s += 128) {
        const int iy = s / 14;           // 0..13
        const int ix = s % 14;           // 0..13
        const float y = y1 + (iy >> 1) * bin_h + ((iy & 1) + 0.5f) * bin_h * 0.5f;
        const float x = x1 + (ix >> 1) * bin_w + ((ix & 1) + 0.5f) * bin_w * 0.5f;
        const float validf =
            (y > -1.0f && y < (float)FH && x > -1.0f && x < (float)FW) ? 1.0f : 0.0f;
        const float yc = fminf(fmaxf(y, 0.0f), (float)(FH - 1));
        const float xc = fminf(fmaxf(x, 0.0f), (float)(FW - 1));
        const int y0 = (int)floorf(yc);
        const int x0 = (int)floorf(xc);
        const int y1i = min(y0 + 1, FH - 1);
        const int x1i = min(x0 + 1, FW - 1);
        const float ly = yc - (float)y0;
        const float lx = xc - (float)x0;
        const float hy = 1.0f - ly;
        const float hx = 1.0f - lx;
        s_off[s][0] = (y0  * FW + x0 ) * CN;
        s_off[s][1] = (y0  * FW + x1i) * CN;
        s_off[s][2] = (y1i * FW + x0 ) * CN;
        s_off[s][3] = (y1i * FW + x1i) * CN;
        s_w[s][0] = hy * hx * validf;
        s_w[s][1] = hy * lx * validf;
        s_w[s][2] = ly * hx * validf;
        s_w[s][3] = ly * lx * validf;
    }
    if (t == 0) s_b = (int)s_roi[0];
    __syncthreads();

    const unsigned short* base = ws + (size_t)s_b * (PLANE * CN) + 2 * t;
    const size_t outbase = ((size_t)r * CN + 2 * t) * (OUT_H * OUT_W);

#pragma unroll 1
    for (int ph = 0; ph < OUT_H; ++ph) {
        float acc0[OUT_W] = {0.f, 0.f, 0.f, 0.f, 0.f, 0.f, 0.f};
        float acc1[OUT_W] = {0.f, 0.f, 0.f, 0.f, 0.f, 0.f, 0.f};
#pragma unroll
        for (int gy = 0; gy < 2; ++gy) {
            const int iy = 2 * ph + gy;
#pragma unroll
            for (int ix = 0; ix < 14; ++ix) {
                const int s = iy * 14 + ix;
                const int pw = ix >> 1;
#pragma unroll
                for (int k = 0; k < 4; ++k) {
                    const unsigned int u = *(const unsigned int*)(base + s_off[s][k]);
                    const float f0 = __uint_as_float(u << 16);
                    const float f1 = __uint_as_float(u & 0xFFFF0000u);
                    const float w = s_w[s][k];
                    acc0[pw] = fmaf(w, f0, acc0[pw]);
                    acc1[pw] = fmaf(w, f1, acc1[pw]);
                }
            }
        }
        const size_t ob = outbase + (size_t)ph * OUT_W;
#pragma unroll
        for (int pw = 0; pw < OUT_W; ++pw) {
            out[ob + pw] = acc0[pw] * 0.25f;
            out[ob + (OUT_H * OUT_W) + pw] = acc1[pw] * 0.25f;
        }
    }
}

// ---------------- fallback: NCHW gather (round-1 kernel) ----------------
__global__ __launch_bounds__(256) void roi_align_nchw(
    const float* __restrict__ feat,
    const float* __restrict__ rois,
    float* __restrict__ out)
{
    const int r  = blockIdx.x;
    const int ph = blockIdx.y;
    const int c  = threadIdx.x;

    __shared__ float s_roi[5];
    __shared__ int   s_off[28][4];
    __shared__ float s_w[28][4];
    __shared__ int   s_b;

    if (threadIdx.x < 5) s_roi[threadIdx.x] = rois[r * 5 + threadIdx.x];
    __syncthreads();

    if (threadIdx.x < 28) {
        const int s  = threadIdx.x;
        const int gy = s / 14;
        const int ix = s % 14;
        const float x1 = s_roi[1] * SPATIAL_SCALE - 0.5f;
        const float y1 = s_roi[2] * SPATIAL_SCALE - 0.5f;
        const float x2 = s_roi[3] * SPATIAL_SCALE - 0.5f;
        const float y2 = s_roi[4] * SPATIAL_SCALE - 0.5f;
        const float bin_w = (x2 - x1) / OUT_W;
        const float bin_h = (y2 - y1) / OUT_H;
        const float y = y1 + ph * bin_h + (gy + 0.5f) * bin_h * 0.5f;
        const int px = ix >> 1;
        const int gx = ix & 1;
        const float x = x1 + px * bin_w + (gx + 0.5f) * bin_w * 0.5f;
        const float validf =
            (y > -1.0f && y < (float)FH && x > -1.0f && x < (float)FW) ? 1.0f : 0.0f;
        const float yc = fminf(fmaxf(y, 0.0f), (float)(FH - 1));
        const float xc = fminf(fmaxf(x, 0.0f), (float)(FW - 1));
        const int y0 = (int)floorf(yc);
        const int x0 = (int)floorf(xc);
        const int y1i = min(y0 + 1, FH - 1);
        const int x1i = min(x0 + 1, FW - 1);
        const float ly = yc - (float)y0;
        const float lx = xc - (float)x0;
        const float hy = 1.0f - ly;
        const float hx = 1.0f - lx;
        s_off[s][0] = y0  * FW + x0;
        s_off[s][1] = y0  * FW + x1i;
        s_off[s][2] = y1i * FW + x0;
        s_off[s][3] = y1i * FW + x1i;
        s_w[s][0] = hy * hx * validf;
        s_w[s][1] = hy * lx * validf;
        s_w[s][2] = ly * hx * validf;
        s_w[s][3] = ly * lx * validf;
    }
    if (threadIdx.x == 0) s_b = (int)s_roi[0];
    __syncthreads();

    const float* base = feat + ((size_t)s_b * CN + c) * PLANE;

    float acc[OUT_W] = {0.f, 0.f, 0.f, 0.f, 0.f, 0.f, 0.f};
#pragma unroll
    for (int s = 0; s < 28; ++s) {
        const float v0 = base[s_off[s][0]];
        const float v1 = base[s_off[s][1]];
        const float v2 = base[s_off[s][2]];
        const float v3 = base[s_off[s][3]];
        acc[(s % 14) >> 1] += s_w[s][0] * v0 + s_w[s][1] * v1 +
                              s_w[s][2] * v2 + s_w[s][3] * v3;
    }

    const size_t outbase = ((size_t)r * CN + c) * (OUT_H * OUT_W) + (size_t)ph * OUT_W;
#pragma unroll
    for (int pw = 0; pw < OUT_W; ++pw) {
        out[outbase + pw] = acc[pw] * 0.25f;
    }
}

extern "C" void kernel_launch(void* const* d_in, const int* in_sizes, int n_in,
                              void* d_out, int out_size, void* d_ws, size_t ws_size,
                              hipStream_t stream) {
    const float* feat = (const float*)d_in[0];
    const float* rois = (const float*)d_in[1];
    float* out = (float*)d_out;

    if (ws_size >= NHWC_BF16_BYTES) {
        unsigned short* ws = (unsigned short*)d_ws;
        dim3 tgrid(N_IMG * FH, FW / 16, 1);          // 400 x 19 = 7600 blocks
        nchw_to_nhwc_bf16<<<tgrid, dim3(256, 1, 1), 0, stream>>>(feat, ws);
        roi_align_roi_block<<<dim3(N_ROIS, 1, 1), dim3(128, 1, 1), 0, stream>>>(ws, rois, out);
    } else {
        dim3 grid(N_ROIS, OUT_H, 1);
        roi_align_nchw<<<grid, dim3(256, 1, 1), 0, stream>>>(feat, rois, out);
    }
}

// Round 5
// 229.254 us; speedup vs baseline: 1.0766x; 1.0766x over previous
//
#include <hip/hip_runtime.h>

// RoIAlign: features (2,256,200,304) fp32 NCHW, rois (512,5) fp32,
// out (512,256,7,7) fp32. OUT=7x7, sampling ratio G=2, scale 0.25.
//
// Round 5: revert to (roi, ph) grid (3584 blocks, 28 waves/CU) — round 4's
// one-block-per-roi starved occupancy (4 waves/CU) and regressed. Write
// amplification (75 vs 25.7 MB) is attacked with an XCD swizzle instead:
// 1-D grid remapped so all 7 ph-blocks of a roi share (id % 8) -> same XCD
// -> its L2 merges the interleaved 28 B runs into dense lines.
// Transpose: 2 channels/lane, packed uint stores (halves store-inst count).

#define OUT_H 7
#define OUT_W 7
constexpr float SPATIAL_SCALE = 0.25f;
constexpr int CN = 256;   // channels
constexpr int FH = 200;
constexpr int FW = 304;
constexpr int N_IMG = 2;
constexpr int N_ROIS = 512;
constexpr size_t PLANE = (size_t)FH * FW;
constexpr size_t NHWC_ELEMS = (size_t)N_IMG * PLANE * CN;
constexpr size_t NHWC_BF16_BYTES = NHWC_ELEMS * sizeof(unsigned short);

__device__ __forceinline__ unsigned short f2bf_rne(float f) {
    unsigned int u = __float_as_uint(f);
    unsigned int r = (u + 0x7FFFu + ((u >> 16) & 1u)) >> 16;  // RNE
    return (unsigned short)r;
}

// ---------------- transpose NCHW fp32 -> NHWC bf16 ----------------
// grid (N_IMG*FH, FW/16); 128 threads, 2 channels per lane (c=2t, 2t+1).
// Reads: each lane reads 2 channel-rows' 64B lines (float4 x 8, all dense).
// Writes: packed bf16x2 as uint -> 256 B contiguous per wave-instruction;
// 16 uint stores per lane (half the store instructions of 1-ch/ushort).
__global__ __launch_bounds__(128) void nchw_to_nhwc_bf16(
    const float* __restrict__ in, unsigned short* __restrict__ ws)
{
    const int nh = blockIdx.x;            // n*FH + h
    const int n = nh / FH;
    const int h = nh % FH;
    const int c0 = 2 * threadIdx.x;       // channels c0, c0+1
    const int w0 = blockIdx.y * 16;

    const float* src0 = in + (((size_t)n * CN + c0) * FH + h) * FW + w0;
    const float* src1 = src0 + (size_t)FH * FW;
    unsigned int* dst =
        (unsigned int*)(ws + (((size_t)n * FH + h) * FW + w0) * CN + c0);

    float4 a0 = *(const float4*)(src0 + 0);
    float4 a1 = *(const float4*)(src0 + 4);
    float4 a2 = *(const float4*)(src0 + 8);
    float4 a3 = *(const float4*)(src0 + 12);
    float4 b0 = *(const float4*)(src1 + 0);
    float4 b1 = *(const float4*)(src1 + 4);
    float4 b2 = *(const float4*)(src1 + 8);
    float4 b3 = *(const float4*)(src1 + 12);

    const float va[16] = {a0.x, a0.y, a0.z, a0.w, a1.x, a1.y, a1.z, a1.w,
                          a2.x, a2.y, a2.z, a2.w, a3.x, a3.y, a3.z, a3.w};
    const float vb[16] = {b0.x, b0.y, b0.z, b0.w, b1.x, b1.y, b1.z, b1.w,
                          b2.x, b2.y, b2.z, b2.w, b3.x, b3.y, b3.z, b3.w};
#pragma unroll
    for (int i = 0; i < 16; ++i) {
        const unsigned int lo = f2bf_rne(va[i]);
        const unsigned int hi = f2bf_rne(vb[i]);
        dst[(size_t)i * (CN / 2)] = lo | (hi << 16);
    }
}

// ---------------- gather on NHWC bf16: (roi, ph) blocks, XCD-swizzled ----
// 1-D grid of 3584; decode so all 7 ph of a roi share (id % 8) => same XCD.
__global__ __launch_bounds__(128) void roi_align_nhwc_bf16(
    const unsigned short* __restrict__ ws,
    const float* __restrict__ rois,
    float* __restrict__ out)
{
    const int b = blockIdx.x;
    const int x = b & 7;                 // XCD residue
    const int s_id = b >> 3;             // 0..447
    const int r  = (s_id / 7) * 8 + x;   // roi
    const int ph = s_id % 7;             // output row
    const int t  = threadIdx.x;          // channel pair: 2t, 2t+1

    __shared__ float s_roi[5];
    __shared__ int   s_off[28][4];
    __shared__ float s_w[28][4];
    __shared__ int   s_b;

    if (t < 5) s_roi[t] = rois[r * 5 + t];
    __syncthreads();

    if (t < 28) {
        const int s  = t;
        const int gy = s / 14;
        const int ix = s % 14;
        const float x1 = s_roi[1] * SPATIAL_SCALE - 0.5f;
        const float y1 = s_roi[2] * SPATIAL_SCALE - 0.5f;
        const float x2 = s_roi[3] * SPATIAL_SCALE - 0.5f;
        const float y2 = s_roi[4] * SPATIAL_SCALE - 0.5f;
        const float bin_w = (x2 - x1) / OUT_W;
        const float bin_h = (y2 - y1) / OUT_H;
        const float y = y1 + ph * bin_h + (gy + 0.5f) * bin_h * 0.5f;
        const float xf = x1 + (ix >> 1) * bin_w + ((ix & 1) + 0.5f) * bin_w * 0.5f;
        const float validf =
            (y > -1.0f && y < (float)FH && xf > -1.0f && xf < (float)FW) ? 1.0f : 0.0f;
        const float yc = fminf(fmaxf(y, 0.0f), (float)(FH - 1));
        const float xc = fminf(fmaxf(xf, 0.0f), (float)(FW - 1));
        const int y0 = (int)floorf(yc);
        const int x0 = (int)floorf(xc);
        const int y1i = min(y0 + 1, FH - 1);
        const int x1i = min(x0 + 1, FW - 1);
        const float ly = yc - (float)y0;
        const float lx = xc - (float)x0;
        const float hy = 1.0f - ly;
        const float hx = 1.0f - lx;
        s_off[s][0] = (y0  * FW + x0 ) * CN;
        s_off[s][1] = (y0  * FW + x1i) * CN;
        s_off[s][2] = (y1i * FW + x0 ) * CN;
        s_off[s][3] = (y1i * FW + x1i) * CN;
        s_w[s][0] = hy * hx * validf;
        s_w[s][1] = hy * lx * validf;
        s_w[s][2] = ly * hx * validf;
        s_w[s][3] = ly * lx * validf;
    }
    if (t == 0) s_b = (int)s_roi[0];
    __syncthreads();

    const unsigned short* base = ws + (size_t)s_b * (PLANE * CN) + 2 * t;

    float acc0[OUT_W] = {0.f, 0.f, 0.f, 0.f, 0.f, 0.f, 0.f};
    float acc1[OUT_W] = {0.f, 0.f, 0.f, 0.f, 0.f, 0.f, 0.f};
#pragma unroll
    for (int s = 0; s < 28; ++s) {
        const int pw = (s % 14) >> 1;
#pragma unroll
        for (int k = 0; k < 4; ++k) {
            const unsigned int u = *(const unsigned int*)(base + s_off[s][k]);
            const float f0 = __uint_as_float(u << 16);
            const float f1 = __uint_as_float(u & 0xFFFF0000u);
            const float w = s_w[s][k];
            acc0[pw] = fmaf(w, f0, acc0[pw]);
            acc1[pw] = fmaf(w, f1, acc1[pw]);
        }
    }

    const size_t outbase = ((size_t)r * CN + 2 * t) * (OUT_H * OUT_W) + (size_t)ph * OUT_W;
#pragma unroll
    for (int pw = 0; pw < OUT_W; ++pw) {
        out[outbase + pw] = acc0[pw] * 0.25f;
        out[outbase + (OUT_H * OUT_W) + pw] = acc1[pw] * 0.25f;
    }
}

// ---------------- fallback: NCHW gather (round-1 kernel) ----------------
__global__ __launch_bounds__(256) void roi_align_nchw(
    const float* __restrict__ feat,
    const float* __restrict__ rois,
    float* __restrict__ out)
{
    const int r  = blockIdx.x;
    const int ph = blockIdx.y;
    const int c  = threadIdx.x;

    __shared__ float s_roi[5];
    __shared__ int   s_off[28][4];
    __shared__ float s_w[28][4];
    __shared__ int   s_b;

    if (threadIdx.x < 5) s_roi[threadIdx.x] = rois[r * 5 + threadIdx.x];
    __syncthreads();

    if (threadIdx.x < 28) {
        const int s  = threadIdx.x;
        const int gy = s / 14;
        const int ix = s % 14;
        const float x1 = s_roi[1] * SPATIAL_SCALE - 0.5f;
        const float y1 = s_roi[2] * SPATIAL_SCALE - 0.5f;
        const float x2 = s_roi[3] * SPATIAL_SCALE - 0.5f;
        const float y2 = s_roi[4] * SPATIAL_SCALE - 0.5f;
        const float bin_w = (x2 - x1) / OUT_W;
        const float bin_h = (y2 - y1) / OUT_H;
        const float y = y1 + ph * bin_h + (gy + 0.5f) * bin_h * 0.5f;
        const float xf = x1 + (ix >> 1) * bin_w + ((ix & 1) + 0.5f) * bin_w * 0.5f;
        const float validf =
            (y > -1.0f && y < (float)FH && xf > -1.0f && xf < (float)FW) ? 1.0f : 0.0f;
        const float yc = fminf(fmaxf(y, 0.0f), (float)(FH - 1));
        const float xc = fminf(fmaxf(xf, 0.0f), (float)(FW - 1));
        const int y0 = (int)floorf(yc);
        const int x0 = (int)floorf(xc);
        const int y1i = min(y0 + 1, FH - 1);
        const int x1i = min(x0 + 1, FW - 1);
        const float ly = yc - (float)y0;
        const float lx = xc - (float)x0;
        const float hy = 1.0f - ly;
        const float hx = 1.0f - lx;
        s_off[s][0] = y0  * FW + x0;
        s_off[s][1] = y0  * FW + x1i;
        s_off[s][2] = y1i * FW + x0;
        s_off[s][3] = y1i * FW + x1i;
        s_w[s][0] = hy * hx * validf;
        s_w[s][1] = hy * lx * validf;
        s_w[s][2] = ly * hx * validf;
        s_w[s][3] = ly * lx * validf;
    }
    if (threadIdx.x == 0) s_b = (int)s_roi[0];
    __syncthreads();

    const float* base = feat + ((size_t)s_b * CN + c) * PLANE;

    float acc[OUT_W] = {0.f, 0.f, 0.f, 0.f, 0.f, 0.f, 0.f};
#pragma unroll
    for (int s = 0; s < 28; ++s) {
        const float v0 = base[s_off[s][0]];
        const float v1 = base[s_off[s][1]];
        const float v2 = base[s_off[s][2]];
        const float v3 = base[s_off[s][3]];
        acc[(s % 14) >> 1] += s_w[s][0] * v0 + s_w[s][1] * v1 +
                              s_w[s][2] * v2 + s_w[s][3] * v3;
    }

    const size_t outbase = ((size_t)r * CN + c) * (OUT_H * OUT_W) + (size_t)ph * OUT_W;
#pragma unroll
    for (int pw = 0; pw < OUT_W; ++pw) {
        out[outbase + pw] = acc[pw] * 0.25f;
    }
}

extern "C" void kernel_launch(void* const* d_in, const int* in_sizes, int n_in,
                              void* d_out, int out_size, void* d_ws, size_t ws_size,
                              hipStream_t stream) {
    const float* feat = (const float*)d_in[0];
    const float* rois = (const float*)d_in[1];
    float* out = (float*)d_out;

    if (ws_size >= NHWC_BF16_BYTES) {
        unsigned short* ws = (unsigned short*)d_ws;
        dim3 tgrid(N_IMG * FH, FW / 16, 1);          // 400 x 19 = 7600 blocks
        nchw_to_nhwc_bf16<<<tgrid, dim3(128, 1, 1), 0, stream>>>(feat, ws);
        roi_align_nhwc_bf16<<<dim3(N_ROIS * OUT_H, 1, 1), dim3(128, 1, 1), 0, stream>>>(
            ws, rois, out);
    } else {
        dim3 grid(N_ROIS, OUT_H, 1);
        roi_align_nchw<<<grid, dim3(256, 1, 1), 0, stream>>>(feat, rois, out);
    }
}